// Round 8
// baseline (205.127 us; speedup 1.0000x reference)
//
#include <hip/hip_runtime.h>
#include <math.h>

#define Bb 8
#define Cc 64
#define Nn 256
#define FD 128
#define ROWS 64          // rows per segment
#define TILE (Nn * FD)   // 32768 floats per (b,c)
#define GRID (Bb * Cc)   // 512 blocks, one per (b,c)

typedef float floatx4 __attribute__((ext_vector_type(4)));

// ---------------------------------------------------------------------------
// fused: one block per (b,c). Phase 1: single pass over the 128 KB tile
// (4 segments of 64 rows), caching segment 0 in LDS; per-row mask logit
// reduce + deferred mask-weighted partials (6 values per bc -> bpart).
// Device-scope spin barrier (threadfence + atomic counter, 2x co-residency
// margin). Phase 2: redundant per-channel finalize (softmax weights for all
// 8 b, BN scale/shift), then elementwise elu(fma(h,w*scale,shift)) — seg 0
// from LDS, segs 1-3 from L2/L3 — with nontemporal stores.
// ---------------------------------------------------------------------------
__global__ __launch_bounds__(256, 2) void fused(
    const float* __restrict__ h, const float* __restrict__ op,
    const float* __restrict__ opS, const float* __restrict__ opQ,
    const float* __restrict__ gamma, const float* __restrict__ beta,
    float* __restrict__ bpart, unsigned int* __restrict__ counter,
    float* __restrict__ out) {
  const int bc = blockIdx.x;
  const int c = bc & (Cc - 1), bmine = bc >> 6;
  const float* __restrict__ tile = h + (size_t)bc * TILE;
  const int tid = threadIdx.x, lane = tid & 63, wv = tid >> 6;
  const int hw = tid >> 5, hl = tid & 31;

  __shared__ float4 s_cache[2048];          // seg 0 tile slice (32 KB)
  __shared__ float s_dh[ROWS];
  __shared__ unsigned long long s_mask[4];
  __shared__ float s_red[4][6];
  __shared__ float s_cs;
  __shared__ float s_S[Bb], s_SS[Bb], s_ws[2 * Bb];
  __shared__ float s_a[Nn];

  // ---- const_src = <source_row, op[c][0:FD]> (wave 0) ----
  if (wv == 0) {
    const float* __restrict__ opc = op + c * 2 * FD;
    float a = tile[lane], b2 = tile[lane + 64];
    float cs = a * opc[lane] + b2 * opc[lane + 64];
#pragma unroll
    for (int off = 32; off >= 1; off >>= 1) cs += __shfl_xor(cs, off, 64);
    if (lane == 0) s_cs = cs;
  }

  const float4 oH = ((const float4*)(op  + c * 2 * FD + FD))[hl];
  const float4 oS = ((const float4*)(opS + c * 2 * FD))[hl];
  const float4 oQ = ((const float4*)(opQ + c * 2 * FD))[hl];
  const float4* __restrict__ tile4 = (const float4*)tile;

  float a_ds = 0, a_dq = 0, a_rsm = 0, a_rsq = 0, a_rssm = 0, a_rssq = 0;

  for (int seg = 0; seg < 4; ++seg) {
    float4 v[8];
    // batched loads: 8 float4 in flight per lane
#pragma unroll
    for (int i = 0; i < 8; ++i)
      v[i] = tile4[(size_t)(seg * ROWS + hw * 8 + i) * 32 + hl];
    if (seg == 0) {
#pragma unroll
      for (int i = 0; i < 8; ++i) s_cache[(hw * 8 + i) * 32 + hl] = v[i];
    }
    float dsp[8], dqp[8], rsp[8], rssp[8];
#pragma unroll
    for (int i = 0; i < 8; ++i) {
      float dh = v[i].x * oH.x + v[i].y * oH.y + v[i].z * oH.z + v[i].w * oH.w;
      dsp[i]  = v[i].x * oS.x + v[i].y * oS.y + v[i].z * oS.z + v[i].w * oS.w;
      dqp[i]  = v[i].x * oQ.x + v[i].y * oQ.y + v[i].z * oQ.z + v[i].w * oQ.w;
      rsp[i]  = v[i].x + v[i].y + v[i].z + v[i].w;
      rssp[i] = v[i].x * v[i].x + v[i].y * v[i].y + v[i].z * v[i].z + v[i].w * v[i].w;
#pragma unroll
      for (int off = 16; off >= 1; off >>= 1) dh += __shfl_xor(dh, off, 64);
      if (hl == 0) s_dh[hw * 8 + i] = dh;
    }
    __syncthreads();
    const float cs = s_cs;
    if (wv == 0) {
      const bool m = (s_dh[lane] + cs) >= 0.0f;
      const unsigned long long bits = __ballot(m);
      if (lane == 0) s_mask[seg] = bits;
    }
#pragma unroll
    for (int i = 0; i < 8; ++i) {
      const bool m = (s_dh[hw * 8 + i] + cs) >= 0.0f;
      a_ds   += m ? dsp[i]  : 0.0f;
      a_dq   += m ? 0.0f    : dqp[i];
      a_rsm  += m ? rsp[i]  : 0.0f;
      a_rsq  += m ? 0.0f    : rsp[i];
      a_rssm += m ? rssp[i] : 0.0f;
      a_rssq += m ? 0.0f    : rssp[i];
    }
    __syncthreads();   // s_dh reused next seg
  }

  // block-wide 6-value reduce
#pragma unroll
  for (int off = 32; off >= 1; off >>= 1) {
    a_ds   += __shfl_xor(a_ds,   off, 64);
    a_dq   += __shfl_xor(a_dq,   off, 64);
    a_rsm  += __shfl_xor(a_rsm,  off, 64);
    a_rsq  += __shfl_xor(a_rsq,  off, 64);
    a_rssm += __shfl_xor(a_rssm, off, 64);
    a_rssq += __shfl_xor(a_rssq, off, 64);
  }
  if (lane == 0) {
    s_red[wv][0] = a_ds;  s_red[wv][1] = a_dq;  s_red[wv][2] = a_rsm;
    s_red[wv][3] = a_rsq; s_red[wv][4] = a_rssm; s_red[wv][5] = a_rssq;
  }
  __syncthreads();
  if (tid < 6) {
    bpart[(size_t)bc * 8 + tid] =
        s_red[0][tid] + s_red[1][tid] + s_red[2][tid] + s_red[3][tid];
  }

  // ---- device-scope barrier (threadFenceReduction pattern) ----
  __threadfence();
  __syncthreads();
  if (tid == 0) {
    atomicAdd(counter, 1u);
    while (__hip_atomic_load(counter, __ATOMIC_ACQUIRE,
                             __HIP_MEMORY_SCOPE_AGENT) < (unsigned)GRID) {
      __builtin_amdgcn_s_sleep(8);
    }
    __threadfence();
  }
  __syncthreads();

  // ---- Phase 2a: redundant finalize (8 half-waves -> 8 batch entries) ----
  volatile const float* bp = bpart;
  const int b = hw;
  const int bcb = b * Cc + c;
  const float4 s4 = ((const float4*)(h + (size_t)bcb * TILE))[hl];  // source row
  const float4 oSs = ((const float4*)(opS + c * 2 * FD + FD))[hl];
  const float4 oQs = ((const float4*)(opQ + c * 2 * FD + FD))[hl];
  float ss = s4.x * oSs.x + s4.y * oSs.y + s4.z * oSs.z + s4.w * oSs.w;
  float qq = s4.x * oQs.x + s4.y * oQs.y + s4.z * oQs.z + s4.w * oQs.w;
#pragma unroll
  for (int off = 16; off >= 1; off >>= 1) {   // stays within half-wave
    ss += __shfl_xor(ss, off, 64);
    qq += __shfl_xor(qq, off, 64);
  }
  float aj = 0.0f;
  if (hl < 6) aj = bp[(size_t)bcb * 8 + hl];
  const int base = lane & 32;
  float a0 = __shfl(aj, base + 0, 64), a1 = __shfl(aj, base + 1, 64);
  float a2 = __shfl(aj, base + 2, 64), a3 = __shfl(aj, base + 3, 64);
  float a4 = __shfl(aj, base + 4, 64), a5 = __shfl(aj, base + 5, 64);

  float sa = a0 * (1.0f / Nn) + ss;
  float qa = a1 * (1.0f / Nn) + qq;
  float mx = fmaxf(sa, qa);
  float es = __expf(sa - mx), eq = __expf(qa - mx);
  float inv = 1.0f / (es + eq);
  float w_s = es * inv, w_q = eq * inv;
  if (hl == 0) {
    s_S[b]  = w_s * a2 + w_q * a3;
    s_SS[b] = w_s * w_s * a4 + w_q * w_q * a5;
    s_ws[2 * b] = w_s; s_ws[2 * b + 1] = w_q;
  }
  __syncthreads();

  float S = 0.0f, SS = 0.0f;
#pragma unroll
  for (int k = 0; k < Bb; ++k) { S += s_S[k]; SS += s_SS[k]; }
  const float invcnt = 1.0f / (float)(Bb * Nn * FD);
  const float mean = S * invcnt;
  const float var  = SS * invcnt - mean * mean;
  const float scale = gamma[c] * rsqrtf(var + 1e-5f);
  const float shift = beta[c] - mean * scale;

  {  // per-row multiplier for own bc
    const int r = tid;
    const unsigned long long m = s_mask[r >> 6];
    const float w = ((m >> (r & 63)) & 1ull) ? s_ws[2 * bmine] : s_ws[2 * bmine + 1];
    s_a[r] = w * scale;
  }
  __syncthreads();

  // ---- Phase 2b: elementwise. seg 0 from LDS, segs 1-3 from cache hierarchy.
  floatx4* __restrict__ o4 = (floatx4*)(out + (size_t)bc * TILE);
#pragma unroll
  for (int k = 0; k < 8; ++k) {           // idx 0..2047 (rows 0..63): LDS
    const int idx = k * 256 + tid;
    const float a = s_a[idx >> 5];
    float4 v = s_cache[idx];
    floatx4 r;
    r.x = fmaf(v.x, a, shift);
    r.y = fmaf(v.y, a, shift);
    r.z = fmaf(v.z, a, shift);
    r.w = fmaf(v.w, a, shift);
    r.x = r.x > 0.0f ? r.x : __expf(r.x) - 1.0f;
    r.y = r.y > 0.0f ? r.y : __expf(r.y) - 1.0f;
    r.z = r.z > 0.0f ? r.z : __expf(r.z) - 1.0f;
    r.w = r.w > 0.0f ? r.w : __expf(r.w) - 1.0f;
    __builtin_nontemporal_store(r, &o4[idx]);
  }
#pragma unroll 4
  for (int k = 8; k < 32; ++k) {          // idx 2048..8191: global (L2/L3)
    const int idx = k * 256 + tid;
    const float a = s_a[idx >> 5];
    float4 v = tile4[idx];
    floatx4 r;
    r.x = fmaf(v.x, a, shift);
    r.y = fmaf(v.y, a, shift);
    r.z = fmaf(v.z, a, shift);
    r.w = fmaf(v.w, a, shift);
    r.x = r.x > 0.0f ? r.x : __expf(r.x) - 1.0f;
    r.y = r.y > 0.0f ? r.y : __expf(r.y) - 1.0f;
    r.z = r.z > 0.0f ? r.z : __expf(r.z) - 1.0f;
    r.w = r.w > 0.0f ? r.w : __expf(r.w) - 1.0f;
    __builtin_nontemporal_store(r, &o4[idx]);
  }
}

extern "C" void kernel_launch(void* const* d_in, const int* in_sizes, int n_in,
                              void* d_out, int out_size, void* d_ws, size_t ws_size,
                              hipStream_t stream) {
  const float* h     = (const float*)d_in[0];
  const float* op    = (const float*)d_in[1];
  const float* opS   = (const float*)d_in[2];
  const float* opQ   = (const float*)d_in[3];
  const float* gamma = (const float*)d_in[4];
  const float* beta  = (const float*)d_in[5];
  float* out = (float*)d_out;

  float* bpart = (float*)d_ws;                               // 512*8 floats
  unsigned int* counter = (unsigned int*)((char*)d_ws + 16384);

  hipMemsetAsync(counter, 0, sizeof(unsigned int), stream);
  fused<<<GRID, 256, 0, stream>>>(h, op, opS, opQ, gamma, beta,
                                  bpart, counter, out);
}

// Round 9
// 134.866 us; speedup vs baseline: 1.5210x; 1.5210x over previous
//
#include <hip/hip_runtime.h>
#include <math.h>

#define Bb 8
#define Cc 64
#define Nn 256
#define FD 128
#define SEGS 4
#define ROWS 64          // rows per block
#define TILE (Nn * FD)   // 32768 floats per (b,c)

typedef float floatx4 __attribute__((ext_vector_type(4)));

// ---------------------------------------------------------------------------
// s1: one block per (bc, seg) — 64 rows, single pass over its 32 KB slice.
// Only the mask logit dh is reduced per-row; dotS/dotQ/rowsum/rowsumsq are
// kept as per-lane register partials and folded with the mask AFTER the
// barrier, then reduced once block-wide (6 values).
// Emits: 64-bit row mask + 6 masked block partials
//   [Σm dotS, Σq dotQ, Σm rs, Σq rs, Σm rss, Σq rss]
// ---------------------------------------------------------------------------
__global__ __launch_bounds__(256) void s1(
    const float* __restrict__ h, const float* __restrict__ op,
    const float* __restrict__ opS, const float* __restrict__ opQ,
    unsigned long long* __restrict__ maskbuf, float* __restrict__ bpart) {
  const int blk = blockIdx.x;
  const int bc = blk >> 2, seg = blk & 3;
  const int c = bc & (Cc - 1);
  const float* __restrict__ tile = h + (size_t)bc * TILE;
  const int tid = threadIdx.x, lane = tid & 63, wv = tid >> 6;
  const int hw = tid >> 5, hl = tid & 31;

  __shared__ float s_dh[ROWS];
  __shared__ float s_red[4][6];
  __shared__ float s_cs;

  // wave 0: const_src = <source_row, op[c][0:FD]> -> LDS for all waves
  if (wv == 0) {
    const float* __restrict__ opc = op + c * 2 * FD;
    float a = tile[lane], b = tile[lane + 64];
    float cs = a * opc[lane] + b * opc[lane + 64];
#pragma unroll
    for (int off = 32; off >= 1; off >>= 1) cs += __shfl_xor(cs, off, 64);
    if (lane == 0) s_cs = cs;
  }

  const float4 oH = ((const float4*)(op  + c * 2 * FD + FD))[hl];
  const float4 oS = ((const float4*)(opS + c * 2 * FD))[hl];
  const float4 oQ = ((const float4*)(opQ + c * 2 * FD))[hl];

  float dsp[8], dqp[8], rsp[8], rssp[8];

  // 8 half-waves x 8 rows = 64 rows; one float4 per half-wave-lane per row.
  // Per iteration only dh is butterfly-reduced (5 steps, both halves).
#pragma unroll
  for (int i = 0; i < 8; ++i) {
    const int nl = hw * 8 + i;
    const float4 v = ((const float4*)(tile + (size_t)(seg * ROWS + nl) * FD))[hl];
    float dh = v.x * oH.x + v.y * oH.y + v.z * oH.z + v.w * oH.w;
    dsp[i]  = v.x * oS.x + v.y * oS.y + v.z * oS.z + v.w * oS.w;
    dqp[i]  = v.x * oQ.x + v.y * oQ.y + v.z * oQ.z + v.w * oQ.w;
    rsp[i]  = v.x + v.y + v.z + v.w;
    rssp[i] = v.x * v.x + v.y * v.y + v.z * v.z + v.w * v.w;
#pragma unroll
    for (int off = 16; off >= 1; off >>= 1) dh += __shfl_xor(dh, off, 64);
    if (hl == 0) s_dh[nl] = dh;
  }
  __syncthreads();

  const float cs = s_cs;

  // ballot mask (wave 0 handles all 64 rows)
  if (wv == 0) {
    const bool m = (s_dh[lane] + cs) >= 0.0f;
    const unsigned long long bits = __ballot(m);
    if (lane == 0) maskbuf[blk] = bits;
  }

  // mask-weighted lane-local accumulation over this lane's 8 rows
  float a_ds = 0, a_dq = 0, a_rsm = 0, a_rsq = 0, a_rssm = 0, a_rssq = 0;
#pragma unroll
  for (int i = 0; i < 8; ++i) {
    const bool m = (s_dh[hw * 8 + i] + cs) >= 0.0f;
    a_ds   += m ? dsp[i]  : 0.0f;
    a_dq   += m ? 0.0f    : dqp[i];
    a_rsm  += m ? rsp[i]  : 0.0f;
    a_rsq  += m ? 0.0f    : rsp[i];
    a_rssm += m ? rssp[i] : 0.0f;
    a_rssq += m ? 0.0f    : rssp[i];
  }
  // one full-wave butterfly (6 steps x 6 values)
#pragma unroll
  for (int off = 32; off >= 1; off >>= 1) {
    a_ds   += __shfl_xor(a_ds,   off, 64);
    a_dq   += __shfl_xor(a_dq,   off, 64);
    a_rsm  += __shfl_xor(a_rsm,  off, 64);
    a_rsq  += __shfl_xor(a_rsq,  off, 64);
    a_rssm += __shfl_xor(a_rssm, off, 64);
    a_rssq += __shfl_xor(a_rssq, off, 64);
  }
  if (lane == 0) {
    s_red[wv][0] = a_ds;  s_red[wv][1] = a_dq;
    s_red[wv][2] = a_rsm; s_red[wv][3] = a_rsq;
    s_red[wv][4] = a_rssm; s_red[wv][5] = a_rssq;
  }
  __syncthreads();
  if (tid < 6) {
    bpart[(size_t)blk * 8 + tid] =
        s_red[0][tid] + s_red[1][tid] + s_red[2][tid] + s_red[3][tid];
  }
}

// ---------------------------------------------------------------------------
// s2f: fused finalize + elementwise. One block per (bc, seg).
// Redundantly per block: per-b softmax weights + channel BN scale/shift,
// then elu(fma(h, w*scale, shift)) over the 32 KB slice (L3-hot re-read via
// nontemporal loads), nontemporal stores for the write-once output.
// ---------------------------------------------------------------------------
__global__ __launch_bounds__(256) void s2f(
    const float* __restrict__ h, const unsigned long long* __restrict__ maskbuf,
    const float* __restrict__ bpart, const float* __restrict__ opS,
    const float* __restrict__ opQ, const float* __restrict__ gamma,
    const float* __restrict__ beta, float* __restrict__ out) {
  const int blk = blockIdx.x, bc = blk >> 2, seg = blk & 3;
  const int c = bc & (Cc - 1), bmine = bc >> 6;
  const int tid = threadIdx.x, lane = tid & 63, hw = tid >> 5, hl = tid & 31;
  __shared__ float s_S[Bb], s_SS[Bb], s_ws[2 * Bb];
  __shared__ float s_a[ROWS];

  const int b = hw;                    // 8 half-waves -> 8 batch entries
  const int bcb = b * Cc + c;

  // source dots for (b,c)
  const float4 s4 = ((const float4*)(h + (size_t)bcb * TILE))[hl];
  const float4 oS = ((const float4*)(opS + c * 2 * FD + FD))[hl];
  const float4 oQ = ((const float4*)(opQ + c * 2 * FD + FD))[hl];
  float ss = s4.x * oS.x + s4.y * oS.y + s4.z * oS.z + s4.w * oS.w;
  float qq = s4.x * oQ.x + s4.y * oQ.y + s4.z * oQ.z + s4.w * oQ.w;
#pragma unroll
  for (int off = 16; off >= 1; off >>= 1) {   // stays within half-wave
    ss += __shfl_xor(ss, off, 64);
    qq += __shfl_xor(qq, off, 64);
  }

  // combine the 4 seg-partials (lanes hl<6, one j each)
  float aj = 0.0f;
  if (hl < 6) {
#pragma unroll
    for (int k = 0; k < SEGS; ++k)
      aj += bpart[(size_t)(bcb * SEGS + k) * 8 + hl];
  }
  const int base = lane & 32;
  float a0 = __shfl(aj, base + 0, 64), a1 = __shfl(aj, base + 1, 64);
  float a2 = __shfl(aj, base + 2, 64), a3 = __shfl(aj, base + 3, 64);
  float a4 = __shfl(aj, base + 4, 64), a5 = __shfl(aj, base + 5, 64);

  float sa = a0 * (1.0f / Nn) + ss;
  float qa = a1 * (1.0f / Nn) + qq;
  float mx = fmaxf(sa, qa);
  float es = __expf(sa - mx), eq = __expf(qa - mx);
  float inv = 1.0f / (es + eq);
  float w_s = es * inv, w_q = eq * inv;
  if (hl == 0) {
    s_S[b]  = w_s * a2 + w_q * a3;
    s_SS[b] = w_s * w_s * a4 + w_q * w_q * a5;
    s_ws[2 * b] = w_s; s_ws[2 * b + 1] = w_q;
  }
  __syncthreads();

  // channel stats (all threads redundantly, LDS broadcast reads)
  float S = 0.0f, SS = 0.0f;
#pragma unroll
  for (int k = 0; k < Bb; ++k) { S += s_S[k]; SS += s_SS[k]; }
  const float invcnt = 1.0f / (float)(Bb * Nn * FD);
  const float mean = S * invcnt;
  const float var  = SS * invcnt - mean * mean;
  const float scale = gamma[c] * rsqrtf(var + 1e-5f);
  const float shift = beta[c] - mean * scale;

  if (tid < ROWS) {
    const unsigned long long m = maskbuf[blk];
    const float w = ((m >> tid) & 1ull) ? s_ws[2 * bmine] : s_ws[2 * bmine + 1];
    s_a[tid] = w * scale;
  }
  __syncthreads();

  const floatx4* __restrict__ h4 = (const floatx4*)(h + (size_t)bc * TILE) + seg * 2048;
  floatx4* __restrict__ o4 = (floatx4*)(out + (size_t)bc * TILE) + seg * 2048;
#pragma unroll
  for (int k = 0; k < 8; ++k) {
    const int idx = k * 256 + tid;
    const float a = s_a[idx >> 5];   // 32 float4 per row -> broadcast per 32 lanes
    floatx4 v = __builtin_nontemporal_load(&h4[idx]);
    floatx4 r;
    r.x = fmaf(v.x, a, shift);
    r.y = fmaf(v.y, a, shift);
    r.z = fmaf(v.z, a, shift);
    r.w = fmaf(v.w, a, shift);
    r.x = r.x > 0.0f ? r.x : __expf(r.x) - 1.0f;
    r.y = r.y > 0.0f ? r.y : __expf(r.y) - 1.0f;
    r.z = r.z > 0.0f ? r.z : __expf(r.z) - 1.0f;
    r.w = r.w > 0.0f ? r.w : __expf(r.w) - 1.0f;
    __builtin_nontemporal_store(r, &o4[idx]);
  }
}

extern "C" void kernel_launch(void* const* d_in, const int* in_sizes, int n_in,
                              void* d_out, int out_size, void* d_ws, size_t ws_size,
                              hipStream_t stream) {
  const float* h     = (const float*)d_in[0];
  const float* op    = (const float*)d_in[1];
  const float* opS   = (const float*)d_in[2];
  const float* opQ   = (const float*)d_in[3];
  const float* gamma = (const float*)d_in[4];
  const float* beta  = (const float*)d_in[5];
  float* out = (float*)d_out;

  unsigned long long* maskbuf = (unsigned long long*)d_ws;   // 2048 u64 = 16 KB
  float* bpart = (float*)((char*)d_ws + 16384);              // 2048*8 floats = 64 KB

  s1<<<Bb * Cc * SEGS, 256, 0, stream>>>(h, op, opS, opQ, maskbuf, bpart);
  s2f<<<Bb * Cc * SEGS, 256, 0, stream>>>(h, maskbuf, bpart, opS, opQ, gamma, beta, out);
}

// Round 10
// 134.046 us; speedup vs baseline: 1.5303x; 1.0061x over previous
//
#include <hip/hip_runtime.h>
#include <math.h>

#define Bb 8
#define Cc 64
#define Nn 256
#define FD 128
#define SEGS 4
#define ROWS 64          // rows per block
#define TILE (Nn * FD)   // 32768 floats per (b,c)

typedef float floatx4 __attribute__((ext_vector_type(4)));

// ---------------------------------------------------------------------------
// s1: one block per (bc, seg) — 64 rows, single pass over its 32 KB slice.
// Only the mask logit dh is reduced per-row; dotS/dotQ/rowsum/rowsumsq are
// kept as per-lane register partials and folded with the mask AFTER the
// barrier, then reduced once block-wide (6 values).
// Emits: 64-bit row mask + 6 masked block partials
//   [Σm dotS, Σq dotQ, Σm rs, Σq rs, Σm rss, Σq rss]
// ---------------------------------------------------------------------------
__global__ __launch_bounds__(256) void s1(
    const float* __restrict__ h, const float* __restrict__ op,
    const float* __restrict__ opS, const float* __restrict__ opQ,
    unsigned long long* __restrict__ maskbuf, float* __restrict__ bpart) {
  const int blk = blockIdx.x;
  const int bc = blk >> 2, seg = blk & 3;
  const int c = bc & (Cc - 1);
  const float* __restrict__ tile = h + (size_t)bc * TILE;
  const int tid = threadIdx.x, lane = tid & 63, wv = tid >> 6;
  const int hw = tid >> 5, hl = tid & 31;

  __shared__ float s_dh[ROWS];
  __shared__ float s_red[4][6];
  __shared__ float s_cs;

  // wave 0: const_src = <source_row, op[c][0:FD]> -> LDS for all waves
  if (wv == 0) {
    const float* __restrict__ opc = op + c * 2 * FD;
    float a = tile[lane], b = tile[lane + 64];
    float cs = a * opc[lane] + b * opc[lane + 64];
#pragma unroll
    for (int off = 32; off >= 1; off >>= 1) cs += __shfl_xor(cs, off, 64);
    if (lane == 0) s_cs = cs;
  }

  const float4 oH = ((const float4*)(op  + c * 2 * FD + FD))[hl];
  const float4 oS = ((const float4*)(opS + c * 2 * FD))[hl];
  const float4 oQ = ((const float4*)(opQ + c * 2 * FD))[hl];

  float dsp[8], dqp[8], rsp[8], rssp[8];

  // 8 half-waves x 8 rows = 64 rows; one float4 per half-wave-lane per row.
  // Per iteration only dh is butterfly-reduced (5 steps, both halves).
#pragma unroll
  for (int i = 0; i < 8; ++i) {
    const int nl = hw * 8 + i;
    const float4 v = ((const float4*)(tile + (size_t)(seg * ROWS + nl) * FD))[hl];
    float dh = v.x * oH.x + v.y * oH.y + v.z * oH.z + v.w * oH.w;
    dsp[i]  = v.x * oS.x + v.y * oS.y + v.z * oS.z + v.w * oS.w;
    dqp[i]  = v.x * oQ.x + v.y * oQ.y + v.z * oQ.z + v.w * oQ.w;
    rsp[i]  = v.x + v.y + v.z + v.w;
    rssp[i] = v.x * v.x + v.y * v.y + v.z * v.z + v.w * v.w;
#pragma unroll
    for (int off = 16; off >= 1; off >>= 1) dh += __shfl_xor(dh, off, 64);
    if (hl == 0) s_dh[nl] = dh;
  }
  __syncthreads();

  const float cs = s_cs;

  // ballot mask (wave 0 handles all 64 rows)
  if (wv == 0) {
    const bool m = (s_dh[lane] + cs) >= 0.0f;
    const unsigned long long bits = __ballot(m);
    if (lane == 0) maskbuf[blk] = bits;
  }

  // mask-weighted lane-local accumulation over this lane's 8 rows
  float a_ds = 0, a_dq = 0, a_rsm = 0, a_rsq = 0, a_rssm = 0, a_rssq = 0;
#pragma unroll
  for (int i = 0; i < 8; ++i) {
    const bool m = (s_dh[hw * 8 + i] + cs) >= 0.0f;
    a_ds   += m ? dsp[i]  : 0.0f;
    a_dq   += m ? 0.0f    : dqp[i];
    a_rsm  += m ? rsp[i]  : 0.0f;
    a_rsq  += m ? 0.0f    : rsp[i];
    a_rssm += m ? rssp[i] : 0.0f;
    a_rssq += m ? 0.0f    : rssp[i];
  }
  // one full-wave butterfly (6 steps x 6 values)
#pragma unroll
  for (int off = 32; off >= 1; off >>= 1) {
    a_ds   += __shfl_xor(a_ds,   off, 64);
    a_dq   += __shfl_xor(a_dq,   off, 64);
    a_rsm  += __shfl_xor(a_rsm,  off, 64);
    a_rsq  += __shfl_xor(a_rsq,  off, 64);
    a_rssm += __shfl_xor(a_rssm, off, 64);
    a_rssq += __shfl_xor(a_rssq, off, 64);
  }
  if (lane == 0) {
    s_red[wv][0] = a_ds;  s_red[wv][1] = a_dq;
    s_red[wv][2] = a_rsm; s_red[wv][3] = a_rsq;
    s_red[wv][4] = a_rssm; s_red[wv][5] = a_rssq;
  }
  __syncthreads();
  if (tid < 6) {
    bpart[(size_t)blk * 8 + tid] =
        s_red[0][tid] + s_red[1][tid] + s_red[2][tid] + s_red[3][tid];
  }
}

// ---------------------------------------------------------------------------
// s2f: fused finalize + elementwise. One block per (bc, seg).
// Redundantly per block: per-b softmax weights + channel BN scale/shift,
// then elu(fma(h, w*scale, shift)) over the 32 KB slice (L3-hot re-read with
// DEFAULT loads — nt loads measured slower, R9), nontemporal stores for the
// write-once output (measured faster, R6).
// ---------------------------------------------------------------------------
__global__ __launch_bounds__(256) void s2f(
    const float* __restrict__ h, const unsigned long long* __restrict__ maskbuf,
    const float* __restrict__ bpart, const float* __restrict__ opS,
    const float* __restrict__ opQ, const float* __restrict__ gamma,
    const float* __restrict__ beta, float* __restrict__ out) {
  const int blk = blockIdx.x, bc = blk >> 2, seg = blk & 3;
  const int c = bc & (Cc - 1), bmine = bc >> 6;
  const int tid = threadIdx.x, lane = tid & 63, hw = tid >> 5, hl = tid & 31;
  __shared__ float s_S[Bb], s_SS[Bb], s_ws[2 * Bb];
  __shared__ float s_a[ROWS];

  const int b = hw;                    // 8 half-waves -> 8 batch entries
  const int bcb = b * Cc + c;

  // source dots for (b,c)
  const float4 s4 = ((const float4*)(h + (size_t)bcb * TILE))[hl];
  const float4 oS = ((const float4*)(opS + c * 2 * FD + FD))[hl];
  const float4 oQ = ((const float4*)(opQ + c * 2 * FD + FD))[hl];
  float ss = s4.x * oS.x + s4.y * oS.y + s4.z * oS.z + s4.w * oS.w;
  float qq = s4.x * oQ.x + s4.y * oQ.y + s4.z * oQ.z + s4.w * oQ.w;
#pragma unroll
  for (int off = 16; off >= 1; off >>= 1) {   // stays within half-wave
    ss += __shfl_xor(ss, off, 64);
    qq += __shfl_xor(qq, off, 64);
  }

  // combine the 4 seg-partials (lanes hl<6, one j each)
  float aj = 0.0f;
  if (hl < 6) {
#pragma unroll
    for (int k = 0; k < SEGS; ++k)
      aj += bpart[(size_t)(bcb * SEGS + k) * 8 + hl];
  }
  const int base = lane & 32;
  float a0 = __shfl(aj, base + 0, 64), a1 = __shfl(aj, base + 1, 64);
  float a2 = __shfl(aj, base + 2, 64), a3 = __shfl(aj, base + 3, 64);
  float a4 = __shfl(aj, base + 4, 64), a5 = __shfl(aj, base + 5, 64);

  float sa = a0 * (1.0f / Nn) + ss;
  float qa = a1 * (1.0f / Nn) + qq;
  float mx = fmaxf(sa, qa);
  float es = __expf(sa - mx), eq = __expf(qa - mx);
  float inv = 1.0f / (es + eq);
  float w_s = es * inv, w_q = eq * inv;
  if (hl == 0) {
    s_S[b]  = w_s * a2 + w_q * a3;
    s_SS[b] = w_s * w_s * a4 + w_q * w_q * a5;
    s_ws[2 * b] = w_s; s_ws[2 * b + 1] = w_q;
  }
  __syncthreads();

  // channel stats (all threads redundantly, LDS broadcast reads)
  float S = 0.0f, SS = 0.0f;
#pragma unroll
  for (int k = 0; k < Bb; ++k) { S += s_S[k]; SS += s_SS[k]; }
  const float invcnt = 1.0f / (float)(Bb * Nn * FD);
  const float mean = S * invcnt;
  const float var  = SS * invcnt - mean * mean;
  const float scale = gamma[c] * rsqrtf(var + 1e-5f);
  const float shift = beta[c] - mean * scale;

  if (tid < ROWS) {
    const unsigned long long m = maskbuf[blk];
    const float w = ((m >> tid) & 1ull) ? s_ws[2 * bmine] : s_ws[2 * bmine + 1];
    s_a[tid] = w * scale;
  }
  __syncthreads();

  const float4* __restrict__ h4 = (const float4*)(h + (size_t)bc * TILE) + seg * 2048;
  floatx4* __restrict__ o4 = (floatx4*)(out + (size_t)bc * TILE) + seg * 2048;
#pragma unroll
  for (int k = 0; k < 8; ++k) {
    const int idx = k * 256 + tid;
    const float a = s_a[idx >> 5];   // 32 float4 per row -> broadcast per 32 lanes
    float4 v = h4[idx];
    floatx4 r;
    r.x = fmaf(v.x, a, shift);
    r.y = fmaf(v.y, a, shift);
    r.z = fmaf(v.z, a, shift);
    r.w = fmaf(v.w, a, shift);
    r.x = r.x > 0.0f ? r.x : __expf(r.x) - 1.0f;
    r.y = r.y > 0.0f ? r.y : __expf(r.y) - 1.0f;
    r.z = r.z > 0.0f ? r.z : __expf(r.z) - 1.0f;
    r.w = r.w > 0.0f ? r.w : __expf(r.w) - 1.0f;
    __builtin_nontemporal_store(r, &o4[idx]);
  }
}

extern "C" void kernel_launch(void* const* d_in, const int* in_sizes, int n_in,
                              void* d_out, int out_size, void* d_ws, size_t ws_size,
                              hipStream_t stream) {
  const float* h     = (const float*)d_in[0];
  const float* op    = (const float*)d_in[1];
  const float* opS   = (const float*)d_in[2];
  const float* opQ   = (const float*)d_in[3];
  const float* gamma = (const float*)d_in[4];
  const float* beta  = (const float*)d_in[5];
  float* out = (float*)d_out;

  unsigned long long* maskbuf = (unsigned long long*)d_ws;   // 2048 u64 = 16 KB
  float* bpart = (float*)((char*)d_ws + 16384);              // 2048*8 floats = 64 KB

  s1<<<Bb * Cc * SEGS, 256, 0, stream>>>(h, op, opS, opQ, maskbuf, bpart);
  s2f<<<Bb * Cc * SEGS, 256, 0, stream>>>(h, maskbuf, bpart, opS, opQ, gamma, beta, out);
}